// Round 5
// baseline (231.856 us; speedup 1.0000x reference)
//
#include <hip/hip_runtime.h>

// out[r,g] = act( sum_{s=start[g]}^{start[g+1]-1} x[r,s]*w[s] + b[g] )
// act(z) = leaky(leaky(z,0.1),0.2) == (z>=0 ? z : 0.02*z)
//
// Block = 32 consecutive genes (contiguous s-range; gene_ids sorted) x 8
// row-groups of ROWS=4 rows. Double-buffered pipeline per block:
//   issue loads(t+1) -> reduce(t) from LDS -> ds_write(t+1) -> barrier
// so HBM latency of the next row-group hides under the current reduce.

#define GPB      32    // genes per block
#define ROWS     4     // rows per row-group
#define RG       8     // row-groups per block
#define SPAN_MAX 1024  // max floats per row staged (buf: 2*16KB = 32KB)
#define NT       256
#define MAXIT    ((ROWS * SPAN_MAX / 4 + NT - 1) / NT)  // 4 float4s/thread max

__global__ void seg_bounds_kernel(const int* __restrict__ gene_ids,
                                  int* __restrict__ start, int S, int G) {
    int s = blockIdx.x * blockDim.x + threadIdx.x;
    if (s >= S) return;
    int c = gene_ids[s];
    if (s == 0) {
        for (int g = 0; g <= c; ++g) start[g] = 0;
    } else {
        int p = gene_ids[s - 1];
        for (int g = p + 1; g <= c; ++g) start[g] = s;
    }
    if (s == S - 1) {
        for (int g = c + 1; g <= G; ++g) start[g] = S;
    }
}

__device__ inline float4 load4_safe(const float* __restrict__ p, int s, int n) {
    if (s + 4 <= n) return *(const float4*)(p + s);
    float4 v; v.x = v.y = v.z = v.w = 0.0f;
    if (s + 0 < n) v.x = p[s + 0];
    if (s + 1 < n) v.y = p[s + 1];
    if (s + 2 < n) v.z = p[s + 2];
    return v;
}

__global__ __launch_bounds__(NT) void
gene_linear_kernel(const float* __restrict__ x,
                   const float* __restrict__ w,
                   const float* __restrict__ b,
                   const int* __restrict__ start,
                   float* __restrict__ out,
                   int S, int G, int B) {
    const int tid = threadIdx.x;
    const int g0  = blockIdx.x * GPB;
    const int g1  = min(g0 + GPB, G);
    const int r00 = blockIdx.y * (ROWS * RG);

    const int base    = start[g0];
    const int end     = start[g1];
    const int base_al = base & ~3;
    const int span    = end - base_al;
    const int nv4     = (span + 3) >> 2;

    const int lane   = tid & 7;
    const int g      = g0 + (tid >> 3);
    const bool active = (g < g1);
    int ss0 = 0, ss1 = 0;
    float bias = 0.0f;
    if (active) { ss0 = start[g]; ss1 = start[g + 1]; bias = b[g]; }

    if (span <= SPAN_MAX) {
        __shared__ float buf[2][ROWS * SPAN_MAX];
        const int total4    = nv4 * ROWS;
        const int rowstride = nv4 * 4;                       // floats per row
        const bool fast_tail = (base_al + nv4 * 4 <= S);     // false only at S-end

        // per-thread flattened (rr, v): i = tid + k*NT, rr = i/nv4, v = i%nv4
        const int rrb = (nv4 > 0) ? (tid / nv4) : 0;
        const int vb  = tid - rrb * nv4;

        float4 reg[MAXIT];

        auto stage_load = [&](int t) {
            int rr = rrb, v = vb;
#pragma unroll
            for (int k = 0; k < MAXIT; ++k) {
                const int i = tid + k * NT;
                if (i < total4) {
                    const float* xrow = x + (size_t)(r00 + t * ROWS + rr) * (size_t)S;
                    const int idx = base_al + v * 4;
                    reg[k] = fast_tail ? *(const float4*)(xrow + idx)
                                       : load4_safe(xrow, idx, S);
                }
                v += NT;
                while (v >= nv4) { v -= nv4; ++rr; }
            }
        };
        auto stage_write = [&](int bf) {
#pragma unroll
            for (int k = 0; k < MAXIT; ++k) {
                const int i = tid + k * NT;
                if (i < total4) *(float4*)&buf[bf][i * 4] = reg[k];
            }
        };
        auto reduce_out = [&](int t, int bf) {
            if (!active) return;
            float a0 = 0.f, a1 = 0.f, a2 = 0.f, a3 = 0.f;
            const float* __restrict__ bp = buf[bf];
            for (int s = ss0 + lane; s < ss1; s += 8) {
                const float wv = w[s];
                const int o = s - base_al;
                a0 = fmaf(bp[0 * rowstride + o], wv, a0);
                a1 = fmaf(bp[1 * rowstride + o], wv, a1);
                a2 = fmaf(bp[2 * rowstride + o], wv, a2);
                a3 = fmaf(bp[3 * rowstride + o], wv, a3);
            }
            float acc[ROWS] = {a0, a1, a2, a3};
#pragma unroll
            for (int rr = 0; rr < ROWS; ++rr) {
                float v = acc[rr];
                v += __shfl_xor(v, 1);
                v += __shfl_xor(v, 2);
                v += __shfl_xor(v, 4);
                acc[rr] = v;
            }
            if (lane == 0) {
#pragma unroll
                for (int rr = 0; rr < ROWS; ++rr) {
                    const float z = acc[rr] + bias;
                    out[(size_t)(r00 + t * ROWS + rr) * (size_t)G + g] =
                        (z >= 0.0f) ? z : 0.02f * z;
                }
            }
        };

        // prologue
        stage_load(0);
        stage_write(0);
        __syncthreads();

        int bf = 0;
        for (int t = 0; t < RG; ++t) {
            if (t + 1 < RG) stage_load(t + 1);   // issue next loads early
            reduce_out(t, bf);                    // compute current from LDS
            if (t + 1 < RG) stage_write(bf ^ 1);  // land next into other buffer
            __syncthreads();
            bf ^= 1;
        }
    } else {
        // fallback (span overflow — statistically never): direct global reads
        if (!active) return;
        for (int t = 0; t < RG; ++t) {
            const int r0 = r00 + t * ROWS;
            float acc[ROWS];
#pragma unroll
            for (int rr = 0; rr < ROWS; ++rr) acc[rr] = 0.0f;
            for (int s = ss0 + lane; s < ss1; s += 8) {
                const float wv = w[s];
#pragma unroll
                for (int rr = 0; rr < ROWS; ++rr)
                    acc[rr] = fmaf(x[(size_t)(r0 + rr) * (size_t)S + s], wv, acc[rr]);
            }
#pragma unroll
            for (int rr = 0; rr < ROWS; ++rr) {
                float v = acc[rr];
                v += __shfl_xor(v, 1);
                v += __shfl_xor(v, 2);
                v += __shfl_xor(v, 4);
                acc[rr] = v;
            }
            if (lane == 0) {
#pragma unroll
                for (int rr = 0; rr < ROWS; ++rr) {
                    const float z = acc[rr] + bias;
                    out[(size_t)(r0 + rr) * (size_t)G + g] =
                        (z >= 0.0f) ? z : 0.02f * z;
                }
            }
        }
    }
}

extern "C" void kernel_launch(void* const* d_in, const int* in_sizes, int n_in,
                              void* d_out, int out_size, void* d_ws, size_t ws_size,
                              hipStream_t stream) {
    const float* x        = (const float*)d_in[0];
    const float* w        = (const float*)d_in[1];
    const float* b        = (const float*)d_in[2];
    const int*   gene_ids = (const int*)d_in[3];

    const int S = in_sizes[1];
    const int G = in_sizes[2];
    const int B = in_sizes[0] / S;

    float* out = (float*)d_out;
    int* start = (int*)d_ws;  // (G+1) ints

    // 1) segment boundaries from sorted gene_ids
    {
        int threads = 256;
        int blocks = (S + threads - 1) / threads;
        seg_bounds_kernel<<<blocks, threads, 0, stream>>>(gene_ids, start, S, G);
    }

    // 2) fused segment-dot + bias + double-leaky, double-buffered pipeline
    {
        const int rows_per_block = ROWS * RG;  // 32
        dim3 block(NT, 1, 1);
        dim3 grid((G + GPB - 1) / GPB, (B + rows_per_block - 1) / rows_per_block, 1);
        gene_linear_kernel<<<grid, block, 0, stream>>>(x, w, b, start, out, S, G, B);
    }
}

// Round 6
// 161.719 us; speedup vs baseline: 1.4337x; 1.4337x over previous
//
#include <hip/hip_runtime.h>

// out[r,g] = act( sum_{s=start[g]}^{start[g+1]-1} x[r,s]*w[s] + b[g] )
// act(z) = leaky(leaky(z,0.1),0.2) == (z>=0 ? z : 0.02*z)
//
// No LDS, no barriers. 8 lanes per gene, float4 per lane: one group-iteration
// covers 32 floats >= typical segment (~20), so the inner loop is usually a
// single iteration. w's float4 is masked at segment boundaries once and the
// mask is reused across ROWS=8 batch rows (8 independent fma chains).
// Boundary float4s overlap neighboring genes' segments -> L1 hits, not HBM.
// Every wave streams independently: latency hidden by TLP alone.

#define GROUP 8
#define ROWS  8
#define NT    256

__global__ void seg_bounds_kernel(const int* __restrict__ gene_ids,
                                  int* __restrict__ start, int S, int G) {
    int s = blockIdx.x * blockDim.x + threadIdx.x;
    if (s >= S) return;
    int c = gene_ids[s];
    if (s == 0) {
        for (int g = 0; g <= c; ++g) start[g] = 0;
    } else {
        int p = gene_ids[s - 1];
        for (int g = p + 1; g <= c; ++g) start[g] = s;
    }
    if (s == S - 1) {
        for (int g = c + 1; g <= G; ++g) start[g] = S;
    }
}

__global__ __launch_bounds__(NT) void
gene_linear_kernel(const float* __restrict__ x,
                   const float* __restrict__ w,
                   const float* __restrict__ b,
                   const int* __restrict__ start,
                   float* __restrict__ out,
                   int S, int G, int B) {
    const int tid  = threadIdx.x;
    const int lane = tid & (GROUP - 1);
    const int g    = blockIdx.x * (NT / GROUP) + (tid / GROUP);
    if (g >= G) return;

    const int r0  = blockIdx.y * ROWS;
    const int ss0 = start[g];
    const int ss1 = start[g + 1];
    const int v0  = ss0 >> 2;                 // first float4 slot of the segment

    const float* __restrict__ x0 = x + (size_t)r0 * (size_t)S;

    float acc[ROWS];
#pragma unroll
    for (int rr = 0; rr < ROWS; ++rr) acc[rr] = 0.0f;

    // NOTE: S % 4 == 0 here, so any float4 slot with 4v < ss1 (<= S) stays
    // within the row: e+3 <= 4*floor((S-1)/4)+3 = S-1.
    for (int v = v0 + lane; 4 * v < ss1; v += GROUP) {
        const int e = 4 * v;
        float4 wv = *(const float4*)(w + e);
        // zero w outside [ss0, ss1) — only first/last float4 of the segment
        // are actually partial; branchless, amortized over ROWS rows.
        if (e < ss0 || e + 4 > ss1) {
            wv.x = (e + 0 >= ss0 && e + 0 < ss1) ? wv.x : 0.0f;
            wv.y = (e + 1 >= ss0 && e + 1 < ss1) ? wv.y : 0.0f;
            wv.z = (e + 2 >= ss0 && e + 2 < ss1) ? wv.z : 0.0f;
            wv.w = (e + 3 >= ss0 && e + 3 < ss1) ? wv.w : 0.0f;
        }
#pragma unroll
        for (int rr = 0; rr < ROWS; ++rr) {
            const float4 xv = *(const float4*)(x0 + (size_t)rr * (size_t)S + e);
            acc[rr] = fmaf(xv.x, wv.x, acc[rr]);
            acc[rr] = fmaf(xv.y, wv.y, acc[rr]);
            acc[rr] = fmaf(xv.z, wv.z, acc[rr]);
            acc[rr] = fmaf(xv.w, wv.w, acc[rr]);
        }
    }

    // reduce across the 8-lane group (xor 1,2,4 stays inside the group)
#pragma unroll
    for (int rr = 0; rr < ROWS; ++rr) {
        float v = acc[rr];
        v += __shfl_xor(v, 1);
        v += __shfl_xor(v, 2);
        v += __shfl_xor(v, 4);
        acc[rr] = v;
    }

    if (lane == 0) {
        const float bias = b[g];
        const int rn = min(ROWS, B - r0);
        for (int rr = 0; rr < rn; ++rr) {
            const float z = acc[rr] + bias;
            out[(size_t)(r0 + rr) * (size_t)G + g] = (z >= 0.0f) ? z : 0.02f * z;
        }
    }
}

extern "C" void kernel_launch(void* const* d_in, const int* in_sizes, int n_in,
                              void* d_out, int out_size, void* d_ws, size_t ws_size,
                              hipStream_t stream) {
    const float* x        = (const float*)d_in[0];
    const float* w        = (const float*)d_in[1];
    const float* b        = (const float*)d_in[2];
    const int*   gene_ids = (const int*)d_in[3];

    const int S = in_sizes[1];
    const int G = in_sizes[2];
    const int B = in_sizes[0] / S;

    float* out = (float*)d_out;
    int* start = (int*)d_ws;  // (G+1) ints

    // 1) segment boundaries from sorted gene_ids
    {
        int threads = 256;
        int blocks = (S + threads - 1) / threads;
        seg_bounds_kernel<<<blocks, threads, 0, stream>>>(gene_ids, start, S, G);
    }

    // 2) fused segment-dot + bias + double-leaky; 8 lanes/gene, float4/lane,
    //    8 rows/thread, no LDS, no barriers
    {
        const int genes_per_block = NT / GROUP;  // 32
        dim3 block(NT, 1, 1);
        dim3 grid((G + genes_per_block - 1) / genes_per_block,
                  (B + ROWS - 1) / ROWS, 1);
        gene_linear_kernel<<<grid, block, 0, stream>>>(x, w, b, start, out, S, G, B);
    }
}